// Round 1
// baseline (1503.894 us; speedup 1.0000x reference)
//
#include <hip/hip_runtime.h>
#include <cstdint>
#include <cstddef>

typedef unsigned short ushort_t;
typedef __attribute__((ext_vector_type(8))) short short8;
typedef __attribute__((ext_vector_type(4))) float f32x4;
typedef __attribute__((ext_vector_type(4))) unsigned short u16x4;
typedef __attribute__((ext_vector_type(8))) unsigned short u16x8;

#if __has_builtin(__builtin_amdgcn_exp2f)
#define EXP2(x) __builtin_amdgcn_exp2f(x)
#else
#define EXP2(x) exp2f(x)
#endif

__device__ __forceinline__ ushort_t f2b(float f) {
  unsigned u = __builtin_bit_cast(unsigned, f);
  u += 0x7fffu + ((u >> 16) & 1u);
  return (ushort_t)(u >> 16);
}
__device__ __forceinline__ float b2f(ushort_t b) {
  return __builtin_bit_cast(float, (unsigned)b << 16);
}

// ---------------------------------------------------------------- constants
// B=4, NQ=NK=2048, D=1024, H=8, DK=DV=128, DO=1024
#define ATT_ELEMS ((size_t)32 * 2048 * 2048)   // (H*B)*NQ*NK

enum { MODE_QH = 0, MODE_KH = 1, MODE_VT = 2, MODE_OUT = 3 };

// ---------------------------------------------------------------- mask -> bf16
__global__ __launch_bounds__(256) void cvt_mask_kernel(const float* __restrict__ m,
                                                       ushort_t* __restrict__ mb) {
  size_t i = ((size_t)blockIdx.x * 256 + threadIdx.x) * 4;
  f32x4 v = *(const f32x4*)(m + i);
  u16x4 o = {f2b(v[0]), f2b(v[1]), f2b(v[2]), f2b(v[3])};
  *(u16x4*)(mb + i) = o;
}

// ---------------------------------------------------------------- generic GEMM
// C[M,N] = A[M,K] * B[N,K]^T + bias, 128x128 tile, 4 waves (2x2 of 64x64),
// BK=64, bf16 MFMA 16x16x32, fp32 accumulate.
template <bool AF32, int MODE>
__global__ __launch_bounds__(256) void gemm_kernel(const void* __restrict__ Av,
                                                   const float* __restrict__ Bm,
                                                   const float* __restrict__ bias,
                                                   void* __restrict__ Cout,
                                                   int K, int N) {
  __shared__ __align__(16) ushort_t Alds[128 * 72];
  __shared__ __align__(16) ushort_t Blds[128 * 72];
  const int m0 = blockIdx.x * 128, n0 = blockIdx.y * 128;
  const int t = threadIdx.x, lane = t & 63, w = t >> 6;
  const int quad = lane >> 4, l16 = lane & 15;
  const int wm = w >> 1, wn = w & 1;
  const int srow = t >> 4;          // 0..15
  const int scol = (t & 15) * 4;    // 0..60

  f32x4 acc[4][4];
#pragma unroll
  for (int i = 0; i < 4; i++)
#pragma unroll
    for (int j = 0; j < 4; j++) acc[i][j] = (f32x4)0.f;

  for (int k0 = 0; k0 < K; k0 += 64) {
    __syncthreads();
#pragma unroll
    for (int p = 0; p < 8; p++) {
      int r = p * 16 + srow;
      if constexpr (AF32) {
        const f32x4 va = *(const f32x4*)((const float*)Av + (size_t)(m0 + r) * K + k0 + scol);
        u16x4 oa = {f2b(va[0]), f2b(va[1]), f2b(va[2]), f2b(va[3])};
        *(u16x4*)(&Alds[r * 72 + scol]) = oa;
      } else {
        *(u16x4*)(&Alds[r * 72 + scol]) =
            *(const u16x4*)((const ushort_t*)Av + (size_t)(m0 + r) * K + k0 + scol);
      }
      const f32x4 vb = *(const f32x4*)(Bm + (size_t)(n0 + r) * K + k0 + scol);
      u16x4 ob = {f2b(vb[0]), f2b(vb[1]), f2b(vb[2]), f2b(vb[3])};
      *(u16x4*)(&Blds[r * 72 + scol]) = ob;
    }
    __syncthreads();
#pragma unroll
    for (int ks = 0; ks < 2; ks++) {
      short8 af[4], bfr[4];
#pragma unroll
      for (int mi = 0; mi < 4; mi++)
        af[mi] = *(const short8*)(&Alds[(64 * wm + 16 * mi + l16) * 72 + ks * 32 + quad * 8]);
#pragma unroll
      for (int nj = 0; nj < 4; nj++)
        bfr[nj] = *(const short8*)(&Blds[(64 * wn + 16 * nj + l16) * 72 + ks * 32 + quad * 8]);
#pragma unroll
      for (int mi = 0; mi < 4; mi++)
#pragma unroll
        for (int nj = 0; nj < 4; nj++)
          acc[mi][nj] = __builtin_amdgcn_mfma_f32_16x16x32_bf16(af[mi], bfr[nj], acc[mi][nj], 0, 0, 0);
    }
  }
  // epilogue: C/D layout row = quad*4+r, col = l16
#pragma unroll
  for (int mi = 0; mi < 4; mi++) {
#pragma unroll
    for (int nj = 0; nj < 4; nj++) {
      int gn = n0 + 64 * wn + 16 * nj + l16;
      float bv = bias[gn];
#pragma unroll
      for (int r = 0; r < 4; r++) {
        int gm = m0 + 64 * wm + 16 * mi + 4 * quad + r;
        float v = acc[mi][nj][r] + bv;
        if constexpr (MODE == MODE_QH) {
          int b = gm >> 11, qq = gm & 2047, hh = gn >> 7, dk = gn & 127;
          ((ushort_t*)Cout)[((size_t)((b * 8 + hh) * 2048 + qq)) * 128 + dk] = f2b(v);
        } else if constexpr (MODE == MODE_KH) {
          ((ushort_t*)Cout)[(size_t)gm * 128 + gn] = f2b(v);
        } else if constexpr (MODE == MODE_VT) {
          int b = gm >> 11, nk = gm & 2047;
          ((ushort_t*)Cout)[((size_t)(b * 128 + gn)) * 2048 + nk] = f2b(v);
        } else {
          ((float*)Cout)[(size_t)gm * N + gn] = v;
        }
      }
    }
  }
}

// ---------------------------------------------------------------- fused attention
// grid (NQ/128, H, B), 256 threads (4 waves), wave w owns 32 q-rows.
// Pass 1: S = qh*kh^T*scale + mask  -> running row max m, row sum l (registers only).
// Pass 2: recompute S, p = exp(S-m)/l, write p (fp32) to att_out, p (bf16) -> LDS
//         (aliased onto K tile), O += P*V via MFMA.
__global__ __launch_bounds__(256, 2) void attn_kernel(const ushort_t* __restrict__ qh,
                                                      const ushort_t* __restrict__ kh,
                                                      const ushort_t* __restrict__ vT,
                                                      const ushort_t* __restrict__ maskb,
                                                      float* __restrict__ att_out,
                                                      ushort_t* __restrict__ outh) {
  __shared__ __align__(16) ushort_t Klds[128 * 136];  // K tile / aliased P tile
  __shared__ __align__(16) ushort_t Vlds[128 * 136];  // V^T tile
  const int q0 = blockIdx.x * 128;
  const int h = blockIdx.y, b = blockIdx.z;
  const int t = threadIdx.x, w = t >> 6, lane = t & 63;
  const int quad = lane >> 4, l16 = lane & 15;
  const float SCALE = 0.088388347648318447f;  // 1/sqrt(128)
  const float L2E = 1.4426950408889634f;
  const int srow = t >> 4, scol = (t & 15) * 8;

  // qh fragments held in registers for both passes: A[m=l16][k=quad*8+j]
  short8 aq[2][4];
#pragma unroll
  for (int mi = 0; mi < 2; mi++)
#pragma unroll
    for (int ks = 0; ks < 4; ks++) {
      int qrow = q0 + 32 * w + 16 * mi + l16;
      aq[mi][ks] =
          *(const short8*)(qh + ((size_t)((b * 8 + h) * 2048 + qrow)) * 128 + ks * 32 + quad * 8);
    }

  float m_run[2][4], l_run[2][4];
#pragma unroll
  for (int mi = 0; mi < 2; mi++)
#pragma unroll
    for (int r = 0; r < 4; r++) { m_run[mi][r] = -1e30f; l_run[mi][r] = 0.f; }

  // ---------------- pass 1: stats
  for (int nk0 = 0; nk0 < 2048; nk0 += 128) {
    __syncthreads();
#pragma unroll
    for (int p = 0; p < 8; p++) {
      int r = p * 16 + srow;
      *(u16x8*)(&Klds[r * 136 + scol]) =
          *(const u16x8*)(kh + (size_t)(b * 2048 + nk0 + r) * 128 + scol);
    }
    __syncthreads();
    f32x4 acc[2][8];
#pragma unroll
    for (int mi = 0; mi < 2; mi++)
#pragma unroll
      for (int nj = 0; nj < 8; nj++) acc[mi][nj] = (f32x4)0.f;
#pragma unroll
    for (int ks = 0; ks < 4; ks++) {
      short8 bk[8];
#pragma unroll
      for (int nj = 0; nj < 8; nj++)
        bk[nj] = *(const short8*)(&Klds[(16 * nj + l16) * 136 + ks * 32 + quad * 8]);
#pragma unroll
      for (int mi = 0; mi < 2; mi++)
#pragma unroll
        for (int nj = 0; nj < 8; nj++)
          acc[mi][nj] = __builtin_amdgcn_mfma_f32_16x16x32_bf16(aq[mi][ks], bk[nj], acc[mi][nj], 0, 0, 0);
    }
#pragma unroll
    for (int mi = 0; mi < 2; mi++) {
#pragma unroll
      for (int r = 0; r < 4; r++) {
        int gq = q0 + 32 * w + 16 * mi + 4 * quad + r;
        const ushort_t* mrow = maskb + ((size_t)b * 2048 + gq) * 2048 + nk0;
        float sv[8];
        float vmax = -1e30f;
#pragma unroll
        for (int nj = 0; nj < 8; nj++) {
          float s = acc[mi][nj][r] * SCALE + b2f(mrow[16 * nj + l16]);
          sv[nj] = s;
          vmax = fmaxf(vmax, s);
        }
#pragma unroll
        for (int o = 1; o < 16; o <<= 1) vmax = fmaxf(vmax, __shfl_xor(vmax, o, 16));
        float mnew = fmaxf(m_run[mi][r], vmax);
        float ssum = 0.f;
#pragma unroll
        for (int nj = 0; nj < 8; nj++) ssum += EXP2((sv[nj] - mnew) * L2E);
#pragma unroll
        for (int o = 1; o < 16; o <<= 1) ssum += __shfl_xor(ssum, o, 16);
        l_run[mi][r] = l_run[mi][r] * EXP2((m_run[mi][r] - mnew) * L2E) + ssum;
        m_run[mi][r] = mnew;
      }
    }
  }

  float rinv[2][4];
#pragma unroll
  for (int mi = 0; mi < 2; mi++)
#pragma unroll
    for (int r = 0; r < 4; r++) rinv[mi][r] = 1.f / l_run[mi][r];

  f32x4 oacc[2][8];
#pragma unroll
  for (int mi = 0; mi < 2; mi++)
#pragma unroll
    for (int nj = 0; nj < 8; nj++) oacc[mi][nj] = (f32x4)0.f;

  // ---------------- pass 2: probs + PV
  for (int nk0 = 0; nk0 < 2048; nk0 += 128) {
    __syncthreads();
#pragma unroll
    for (int p = 0; p < 8; p++) {
      int r = p * 16 + srow;
      *(u16x8*)(&Klds[r * 136 + scol]) =
          *(const u16x8*)(kh + (size_t)(b * 2048 + nk0 + r) * 128 + scol);
      *(u16x8*)(&Vlds[r * 136 + scol]) =
          *(const u16x8*)(vT + (size_t)(b * 128 + r) * 2048 + nk0 + scol);
    }
    __syncthreads();
    f32x4 acc[2][8];
#pragma unroll
    for (int mi = 0; mi < 2; mi++)
#pragma unroll
      for (int nj = 0; nj < 8; nj++) acc[mi][nj] = (f32x4)0.f;
#pragma unroll
    for (int ks = 0; ks < 4; ks++) {
      short8 bk[8];
#pragma unroll
      for (int nj = 0; nj < 8; nj++)
        bk[nj] = *(const short8*)(&Klds[(16 * nj + l16) * 136 + ks * 32 + quad * 8]);
#pragma unroll
      for (int mi = 0; mi < 2; mi++)
#pragma unroll
        for (int nj = 0; nj < 8; nj++)
          acc[mi][nj] = __builtin_amdgcn_mfma_f32_16x16x32_bf16(aq[mi][ks], bk[nj], acc[mi][nj], 0, 0, 0);
    }
    __syncthreads();  // all K-tile reads done before aliased P writes
#pragma unroll
    for (int mi = 0; mi < 2; mi++) {
#pragma unroll
      for (int r = 0; r < 4; r++) {
        int gq = q0 + 32 * w + 16 * mi + 4 * quad + r;
        const ushort_t* mrow = maskb + ((size_t)b * 2048 + gq) * 2048 + nk0;
        float* orow = att_out + ((size_t)(h * 4 + b) * 2048 + gq) * 2048 + nk0;
        ushort_t* prow = &Klds[(32 * w + 16 * mi + 4 * quad + r) * 136];
        float mr = m_run[mi][r], ri = rinv[mi][r];
#pragma unroll
        for (int nj = 0; nj < 8; nj++) {
          float s = acc[mi][nj][r] * SCALE + b2f(mrow[16 * nj + l16]);
          float pv = EXP2((s - mr) * L2E) * ri;
          orow[16 * nj + l16] = pv;
          prow[16 * nj + l16] = f2b(pv);
        }
      }
    }
    // PV: A = P (own wave's 32 LDS rows), B = V^T
#pragma unroll
    for (int ks = 0; ks < 4; ks++) {
      short8 ap[2], bv[8];
#pragma unroll
      for (int mi = 0; mi < 2; mi++)
        ap[mi] = *(const short8*)(&Klds[(32 * w + 16 * mi + l16) * 136 + ks * 32 + quad * 8]);
#pragma unroll
      for (int nj = 0; nj < 8; nj++)
        bv[nj] = *(const short8*)(&Vlds[(16 * nj + l16) * 136 + ks * 32 + quad * 8]);
#pragma unroll
      for (int mi = 0; mi < 2; mi++)
#pragma unroll
        for (int nj = 0; nj < 8; nj++)
          oacc[mi][nj] = __builtin_amdgcn_mfma_f32_16x16x32_bf16(ap[mi], bv[nj], oacc[mi][nj], 0, 0, 0);
    }
  }
  // epilogue: outh[b, q, h*128 + dv] bf16
#pragma unroll
  for (int mi = 0; mi < 2; mi++)
#pragma unroll
    for (int nj = 0; nj < 8; nj++)
#pragma unroll
      for (int r = 0; r < 4; r++) {
        int gq = q0 + 32 * w + 16 * mi + 4 * quad + r;
        int dv = 16 * nj + l16;
        outh[(size_t)(b * 2048 + gq) * 1024 + h * 128 + dv] = f2b(oacc[mi][nj][r]);
      }
}

// ---------------------------------------------------------------- launch
extern "C" void kernel_launch(void* const* d_in, const int* in_sizes, int n_in,
                              void* d_out, int out_size, void* d_ws, size_t ws_size,
                              hipStream_t stream) {
  const float* q    = (const float*)d_in[0];
  const float* k    = (const float*)d_in[1];
  const float* v    = (const float*)d_in[2];
  const float* mask = (const float*)d_in[3];
  const float* Wq   = (const float*)d_in[4];
  const float* bq   = (const float*)d_in[5];
  const float* Wk   = (const float*)d_in[6];
  const float* bk   = (const float*)d_in[7];
  const float* Wv   = (const float*)d_in[8];
  const float* bv   = (const float*)d_in[9];
  const float* Wo   = (const float*)d_in[10];
  const float* bo   = (const float*)d_in[11];

  float* att = (float*)d_out;
  float* out = att + ATT_ELEMS;

  char* ws = (char*)d_ws;
  ushort_t* qh_b   = (ushort_t*)(ws);              // 16,777,216 B
  ushort_t* kh_b   = (ushort_t*)(ws + 16777216);   //  2,097,152 B
  ushort_t* vT_b   = (ushort_t*)(ws + 18874368);   //  2,097,152 B
  ushort_t* outh_b = (ushort_t*)(ws + 20971520);   // 16,777,216 B
  ushort_t* mb     = (ushort_t*)(ws + 37748736);   // 33,554,432 B   total ~71.3 MB

  cvt_mask_kernel<<<16384, 256, 0, stream>>>(mask, mb);
  gemm_kernel<true, MODE_QH><<<dim3(64, 8), 256, 0, stream>>>(q, Wq, bq, qh_b, 1024, 1024);
  gemm_kernel<true, MODE_KH><<<dim3(64, 1), 256, 0, stream>>>(k, Wk, bk, kh_b, 1024, 128);
  gemm_kernel<true, MODE_VT><<<dim3(64, 1), 256, 0, stream>>>(v, Wv, bv, vT_b, 1024, 128);
  attn_kernel<<<dim3(16, 8, 4), 256, 0, stream>>>(qh_b, kh_b, vT_b, mb, att, outh_b);
  gemm_kernel<false, MODE_OUT><<<dim3(64, 8), 256, 0, stream>>>(outh_b, Wo, bo, out, 1024, 1024);
}